// Round 1
// baseline (583.026 us; speedup 1.0000x reference)
//
#include <hip/hip_runtime.h>

// LinearAttention (Performer/FAVOR+): B=8, T=S=8192, F=D=64, M=128 (2M=256 features)
// out[b,t,d] = (sum_m qf[t,m]*kv[m,d]) / (sum_m qf[t,m]*kv[m,64])
// kv[m,d]   = sum_s kf[s,m]*v1[s,d],  v1 = [value | 1]
// feat_m(x) = (exp(sgn_m * (x . omega[m%128]) - |x|^2/2) + 1e-9) / 16

constexpr int NB = 8;
constexpr int NT = 8192;
constexpr int NFEAT = 256;        // 2M
constexpr float EPSF = 1e-9f;
constexpr float SCALE = 0.0625f;  // 1/sqrt(2*128)

constexpr int K1_CHUNKS = 64;                  // chunks per batch
constexpr int K1_GRID = NB * K1_CHUNKS;        // 512
constexpr int KV_ROW_PAD = 68;                 // padded partial row (float4-aligned)
constexpr int KV_ELEMS = NB * NFEAT * 65;      // 133120 floats in kvg

// ---------------- Kernel 1: kv partials over S-chunks ----------------
// grid 512 (= NB*64 chunks), block 256. Thread t owns feature m=t.
__global__ __launch_bounds__(256, 1) void k1_kv(
    const float* __restrict__ key,     // [B][S][64]
    const float* __restrict__ value,   // [B][S][64]
    const float* __restrict__ omega,   // [128][64]
    float* __restrict__ kvg,           // [B][256][65]  (atomic fallback)
    float* __restrict__ partial,       // [512][256][68] (partial path)
    int use_partial)
{
  const int t = threadIdx.x;
  const int b = blockIdx.x >> 6;
  const int chunk = blockIdx.x & 63;
  const int s0 = chunk * 128;
  const int lane = t & 63;
  const int wv = t >> 6;
  const int mrow = t & 127;
  const float sgn = (t < 128) ? 1.0f : -1.0f;

  // omega row in registers (16 float4 = 64 VGPR)
  float4 omr[16];
  {
    const float4* om4 = (const float4*)omega;
#pragma unroll
    for (int j = 0; j < 16; ++j) omr[j] = om4[mrow * 16 + j];
  }

  __shared__ __align__(16) float krow[4][64];
  __shared__ __align__(16) float vrow[4][64];
  __shared__ float ssh[4];

  float acc[64];
#pragma unroll
  for (int d = 0; d < 64; ++d) acc[d] = 0.f;
  float acc64 = 0.f;

  const float* keyb = key + (size_t)b * NT * 64;
  const float* valb = value + (size_t)b * NT * 64;

  for (int g = 0; g < 32; ++g) {
    const int r4 = s0 + g * 4;
    // stage 4 rows: wave wv loads row r4+wv; ss via wave butterfly
    {
      float x = keyb[(r4 + wv) * 64 + lane];
      float v = valb[(r4 + wv) * 64 + lane];
      float s2 = x * x;
#pragma unroll
      for (int mm = 32; mm >= 1; mm >>= 1) s2 += __shfl_xor(s2, mm, 64);
      krow[wv][lane] = x;
      vrow[wv][lane] = v;
      if (lane == 0) ssh[wv] = 0.5f * s2;
    }
    __syncthreads();
#pragma unroll
    for (int r = 0; r < 4; ++r) {
      const float4* kr4 = (const float4*)krow[r];  // broadcast reads
      float dot = 0.f;
#pragma unroll
      for (int j = 0; j < 16; ++j) {
        float4 kq = kr4[j];
        float4 o = omr[j];
        dot += kq.x * o.x;
        dot += kq.y * o.y;
        dot += kq.z * o.z;
        dot += kq.w * o.w;
      }
      float feat = (__expf(sgn * dot - ssh[r]) + EPSF) * SCALE;
      const float4* vr4 = (const float4*)vrow[r];  // broadcast reads
#pragma unroll
      for (int j = 0; j < 16; ++j) {
        float4 vv = vr4[j];
        acc[4 * j + 0] += feat * vv.x;
        acc[4 * j + 1] += feat * vv.y;
        acc[4 * j + 2] += feat * vv.z;
        acc[4 * j + 3] += feat * vv.w;
      }
      acc64 += feat;
    }
    __syncthreads();
  }

  if (use_partial) {
    float* dst = partial + (size_t)blockIdx.x * (NFEAT * KV_ROW_PAD) + t * KV_ROW_PAD;
#pragma unroll
    for (int j = 0; j < 16; ++j) {
      float4 w4;
      w4.x = acc[4 * j + 0];
      w4.y = acc[4 * j + 1];
      w4.z = acc[4 * j + 2];
      w4.w = acc[4 * j + 3];
      ((float4*)dst)[j] = w4;
    }
    dst[64] = acc64;
  } else {
    float* dst = kvg + ((size_t)b * NFEAT + t) * 65;
#pragma unroll
    for (int d = 0; d < 64; ++d) atomicAdd(dst + d, acc[d]);
    atomicAdd(dst + 64, acc64);
  }
}

// ---------------- Kernel 1b: reduce partials -> kvg ----------------
__global__ __launch_bounds__(256) void k1b_reduce(
    const float* __restrict__ partial, float* __restrict__ kvg)
{
  int i = blockIdx.x * 256 + threadIdx.x;
  if (i >= KV_ELEMS) return;
  int b = i / (NFEAT * 65);
  int rem = i - b * (NFEAT * 65);
  int m = rem / 65;
  int d = rem - m * 65;
  const float* src = partial + (size_t)(b * K1_CHUNKS) * (NFEAT * KV_ROW_PAD) + m * KV_ROW_PAD + d;
  float s = 0.f;
#pragma unroll 8
  for (int c = 0; c < K1_CHUNKS; ++c) s += src[(size_t)c * (NFEAT * KV_ROW_PAD)];
  kvg[i] = s;
}

// ---------------- Kernel 2: qkv + normalize ----------------
// grid 2048 (= NB*256 row-groups of 32), block 256.
// Thread t owns feature m=t (omega row in regs) AND kv chunk column:
// kvr[mm] = kv[64*wv+mm][lane] (64 VGPR).
__global__ __launch_bounds__(256, 1) void k2_qkv(
    const float* __restrict__ query,   // [B][T][64]
    const float* __restrict__ omega,   // [128][64]
    const float* __restrict__ kvg,     // [B][256][65]
    float* __restrict__ out)           // [B][T][64]
{
  const int t = threadIdx.x;
  const int b = blockIdx.x >> 8;
  const int rb = (blockIdx.x & 255) * 32;
  const int lane = t & 63;
  const int wv = t >> 6;
  const int mrow = t & 127;
  const float sgn = (t < 128) ? 1.0f : -1.0f;

  float4 omr[16];
  {
    const float4* om4 = (const float4*)omega;
#pragma unroll
    for (int j = 0; j < 16; ++j) omr[j] = om4[mrow * 16 + j];
  }

  const float* kvb = kvg + (size_t)b * NFEAT * 65;
  float kvr[64];
#pragma unroll 8
  for (int mm = 0; mm < 64; ++mm) kvr[mm] = kvb[(wv * 64 + mm) * 65 + lane];
  const float kc64 = kvb[t * 65 + 64];

  __shared__ __align__(16) float qrow[4][64];
  __shared__ __align__(16) float qf[4][256];
  __shared__ float part[4][4][64];  // [row][chunk][d]
  __shared__ float ssh[4];
  __shared__ float dnw[4][4];       // [wave][row]

  const float* qb = query + (size_t)b * NT * 64;
  float* ob = out + (size_t)b * NT * 64;

  for (int g = 0; g < 8; ++g) {
    const int r0 = rb + g * 4;
    // stage 4 q rows + ss
    {
      float x = qb[(r0 + wv) * 64 + lane];
      float s2 = x * x;
#pragma unroll
      for (int mm = 32; mm >= 1; mm >>= 1) s2 += __shfl_xor(s2, mm, 64);
      qrow[wv][lane] = x;
      if (lane == 0) ssh[wv] = 0.5f * s2;
    }
    __syncthreads();
    // features for own m, all 4 rows; denominator partial = feat * kv[m][64]
    float denp[4];
#pragma unroll
    for (int rr = 0; rr < 4; ++rr) {
      const float4* qr4 = (const float4*)qrow[rr];
      float dot = 0.f;
#pragma unroll
      for (int j = 0; j < 16; ++j) {
        float4 kq = qr4[j];
        float4 o = omr[j];
        dot += kq.x * o.x;
        dot += kq.y * o.y;
        dot += kq.z * o.z;
        dot += kq.w * o.w;
      }
      float feat = (__expf(sgn * dot - ssh[rr]) + EPSF) * SCALE;
      qf[rr][t] = feat;
      denp[rr] = feat * kc64;
    }
#pragma unroll
    for (int mm = 32; mm >= 1; mm >>= 1) {
#pragma unroll
      for (int rr = 0; rr < 4; ++rr) denp[rr] += __shfl_xor(denp[rr], mm, 64);
    }
    if (lane == 0) {
#pragma unroll
      for (int rr = 0; rr < 4; ++rr) dnw[wv][rr] = denp[rr];
    }
    __syncthreads();
    // numerator partial over chunk wv for column d=lane, all 4 rows
#pragma unroll
    for (int rr = 0; rr < 4; ++rr) {
      const float4* qfr = (const float4*)&qf[rr][wv * 64];  // broadcast reads
      float p = 0.f;
#pragma unroll
      for (int j = 0; j < 16; ++j) {
        float4 q4 = qfr[j];
        p += q4.x * kvr[4 * j + 0];
        p += q4.y * kvr[4 * j + 1];
        p += q4.z * kvr[4 * j + 2];
        p += q4.w * kvr[4 * j + 3];
      }
      part[rr][wv][lane] = p;
    }
    __syncthreads();
    // combine + normalize + store: wave wv writes row r0+wv
    {
      const int rr = wv;
      float num = part[rr][0][lane] + part[rr][1][lane] + part[rr][2][lane] + part[rr][3][lane];
      float den = dnw[0][rr] + dnw[1][rr] + dnw[2][rr] + dnw[3][rr];
      ob[(r0 + rr) * 64 + lane] = num / den;
    }
    __syncthreads();
  }
}

extern "C" void kernel_launch(void* const* d_in, const int* in_sizes, int n_in,
                              void* d_out, int out_size, void* d_ws, size_t ws_size,
                              hipStream_t stream) {
  const float* query = (const float*)d_in[0];  // [8][8192][64]
  const float* value = (const float*)d_in[1];  // [8][8192][64]
  const float* key   = (const float*)d_in[2];  // [8][8192][64]
  const float* omega = (const float*)d_in[3];  // [128][64]
  float* out = (float*)d_out;

  float* kvg = (float*)d_ws;                   // 133120 floats = 532480 B
  float* partial = kvg + KV_ELEMS;             // [512][256][68] floats
  const size_t need = (size_t)KV_ELEMS * 4 + (size_t)K1_GRID * NFEAT * KV_ROW_PAD * 4;
  const int use_partial = (ws_size >= need) ? 1 : 0;

  if (!use_partial) {
    hipMemsetAsync(kvg, 0, (size_t)KV_ELEMS * 4, stream);
  }
  k1_kv<<<K1_GRID, 256, 0, stream>>>(key, value, omega, kvg, partial, use_partial);
  if (use_partial) {
    k1b_reduce<<<(KV_ELEMS + 255) / 256, 256, 0, stream>>>(partial, kvg);
  }
  k2_qkv<<<NB * 256, 256, 0, stream>>>(query, omega, kvg, out);
}

// Round 2
// 166.897 us; speedup vs baseline: 3.4933x; 3.4933x over previous
//
#include <hip/hip_runtime.h>

// LinearAttention (Performer/FAVOR+): B=8, T=S=8192, F=D=64, M=128 (2M=256 features)
// MFMA (16x16x32 bf16) implementation with split-bf16 for the pre-exp x.omega GEMM.
//
// Layouts (measured, learn_hip m89/m91):
//   A-frag: lane holds A[m = lane&15][k = (lane>>4)*8 + j], j=0..7
//   B-frag: lane holds B[k = (lane>>4)*8 + j][n = lane&15]
//   C/D   : lane holds D[row = (lane>>4)*4 + reg][col = lane&15], reg=0..3

constexpr int NB = 8;
constexpr int NT = 8192;
constexpr float EPSF = 1e-9f;
constexpr float SCALE = 0.0625f;  // 1/sqrt(2*128)

typedef short s8v __attribute__((ext_vector_type(8)));
typedef short s4v __attribute__((ext_vector_type(4)));
typedef float f4v __attribute__((ext_vector_type(4)));

__device__ inline f4v mfma16(s8v a, s8v b, f4v c) {
  return __builtin_amdgcn_mfma_f32_16x16x32_bf16(a, b, c, 0, 0, 0);
}

__device__ inline short bf16_rne(float f) {
  unsigned u = __builtin_bit_cast(unsigned, f);
  u += 0x7fffu + ((u >> 16) & 1u);
  return (short)(u >> 16);
}
__device__ inline float bf16_to_f(short h) {
  unsigned u = ((unsigned)(unsigned short)h) << 16;
  return __builtin_bit_cast(float, u);
}

// ---- setup: split omega into bf16 hi/lo ----
__global__ void setup_omega(const float* __restrict__ omega,
                            short* __restrict__ oh, short* __restrict__ ol) {
  int i = blockIdx.x * 256 + threadIdx.x;
  if (i >= 128 * 64) return;
  float w = omega[i];
  short h = bf16_rne(w);
  oh[i] = h;
  ol[i] = bf16_rne(w - bf16_to_f(h));
}

// ---- shared phi helpers ----
struct PhiRows {
  s8v ah0, al0, ah1, al1;  // A-frags (hi/lo) for ksteps 0,1
  float ssr[4];            // |x_row|^2/2 for rows quad*4+reg
};

__device__ inline void split8(f4v a, f4v b, s8v& h, s8v& l) {
  float v[8] = {a.x, a.y, a.z, a.w, b.x, b.y, b.z, b.w};
#pragma unroll
  for (int j = 0; j < 8; ++j) {
    short hh = bf16_rne(v[j]);
    h[j] = hh;
    l[j] = bf16_rne(v[j] - bf16_to_f(hh));
  }
}

// xrow_base points at x[b][row0][0]; loads 16 rows' fragments for this wave.
__device__ inline void load_phi_rows(const float* __restrict__ xrow_base, int lane, PhiRows& P) {
  const int r = lane & 15, q = lane >> 4;
  const float* p = xrow_base + r * 64 + q * 8;
  f4v u0 = *(const f4v*)(p);
  f4v u1 = *(const f4v*)(p + 4);
  f4v u2 = *(const f4v*)(p + 32);
  f4v u3 = *(const f4v*)(p + 36);
  float ss = u0.x * u0.x + u0.y * u0.y + u0.z * u0.z + u0.w * u0.w
           + u1.x * u1.x + u1.y * u1.y + u1.z * u1.z + u1.w * u1.w
           + u2.x * u2.x + u2.y * u2.y + u2.z * u2.z + u2.w * u2.w
           + u3.x * u3.x + u3.y * u3.y + u3.z * u3.z + u3.w * u3.w;
  ss += __shfl_xor(ss, 16, 64);
  ss += __shfl_xor(ss, 32, 64);
  ss *= 0.5f;
#pragma unroll
  for (int reg = 0; reg < 4; ++reg) P.ssr[reg] = __shfl(ss, q * 4 + reg, 64);
  split8(u0, u1, P.ah0, P.al0);
  split8(u2, u3, P.ah1, P.al1);
}

// xw C-tile for feature block f0 (3-way split product).
__device__ inline f4v phi_xw_tile(const PhiRows& P, const short* __restrict__ oh,
                                  const short* __restrict__ ol, int f0, int lane) {
  const int fr = f0 + (lane & 15);
  const int q = lane >> 4;
  s8v bh0 = *(const s8v*)(oh + fr * 64 + q * 8);
  s8v bh1 = *(const s8v*)(oh + fr * 64 + 32 + q * 8);
  s8v bl0 = *(const s8v*)(ol + fr * 64 + q * 8);
  s8v bl1 = *(const s8v*)(ol + fr * 64 + 32 + q * 8);
  f4v c = {0.f, 0.f, 0.f, 0.f};
  c = mfma16(P.ah0, bh0, c);
  c = mfma16(P.ah1, bh1, c);
  c = mfma16(P.al0, bh0, c);
  c = mfma16(P.al1, bh1, c);
  c = mfma16(P.ah0, bl0, c);
  c = mfma16(P.ah1, bl1, c);
  return c;
}

// ---- Kernel KV: fused phi(k) + kv GEMM. grid 512 = 8b x 64 chunks(128 s) ----
constexpr int KF_P = 72;    // kfT pitch (shorts): 64 s + 8 pad
constexpr int KV_BLOCKS_PER_B = 64;
constexpr int KV_PARTIAL_SZ = 80 * 256;  // floats per block

__global__ __launch_bounds__(256, 1) void kv_fused(
    const float* __restrict__ key, const float* __restrict__ value,
    const short* __restrict__ oh, const short* __restrict__ ol,
    float* __restrict__ partial, float* __restrict__ kvg, int use_partial) {
  __shared__ short kft[256 * KF_P];  // [feat][s] bf16, 36.9 KB
  __shared__ short v1t[80 * KF_P];   // [d][s] bf16, 11.5 KB
  const int tid = threadIdx.x, lane = tid & 63, w = tid >> 6;
  const int b = blockIdx.x >> 6;
  const int s0 = (blockIdx.x & 63) * 128;
  const int q = lane >> 4;

  // zero v1t rows 65..79 (padding d-columns of the N=80 tile)
  for (int i = tid; i < 15 * KF_P; i += 256) v1t[65 * KF_P + i] = 0;

  f4v acc[4][5];
#pragma unroll
  for (int j = 0; j < 4; ++j)
#pragma unroll
    for (int n = 0; n < 5; ++n) acc[j][n] = f4v{0.f, 0.f, 0.f, 0.f};

  for (int sc = 0; sc < 2; ++sc) {
    const int sbase = s0 + sc * 64;
    __syncthreads();  // protect previous iteration's GEMM reads
    // stage v1t (transposed, bf16)
    {
      const float* vb = value + ((size_t)b * NT + sbase) * 64;
#pragma unroll
      for (int i = 0; i < 16; ++i) {
        int e = tid + i * 256;
        int s = e >> 6, d = e & 63;
        v1t[d * KF_P + s] = bf16_rne(vb[e]);
      }
      if (tid < 64) v1t[64 * KF_P + tid] = (short)0x3F80;  // bf16(1.0)
    }
    // phi(k) for this wave's 16 rows -> kft
    {
      PhiRows P;
      load_phi_rows(key + ((size_t)b * NT + sbase + w * 16) * 64, lane, P);
#pragma unroll
      for (int ft = 0; ft < 8; ++ft) {
        f4v c = phi_xw_tile(P, oh, ol, ft * 16, lane);
        const int f = ft * 16 + (lane & 15);
        s4v pk, nk;
#pragma unroll
        for (int reg = 0; reg < 4; ++reg) {
          float xw = c[reg];
          pk[reg] = bf16_rne((__expf(xw - P.ssr[reg]) + EPSF) * SCALE);
          nk[reg] = bf16_rne((__expf(-xw - P.ssr[reg]) + EPSF) * SCALE);
        }
        const int scol = w * 16 + q * 4;
        *(s4v*)(kft + f * KF_P + scol) = pk;
        *(s4v*)(kft + (f + 128) * KF_P + scol) = nk;
      }
    }
    __syncthreads();
    // KV GEMM: acc[j][n] += kfT[feat-tile] x v1t
#pragma unroll
    for (int ks = 0; ks < 2; ++ks) {
      s8v bf[5];
#pragma unroll
      for (int n = 0; n < 5; ++n)
        bf[n] = *(const s8v*)(v1t + (n * 16 + (lane & 15)) * KF_P + ks * 32 + q * 8);
#pragma unroll
      for (int j = 0; j < 4; ++j) {
        s8v a = *(const s8v*)(kft + (w * 64 + j * 16 + (lane & 15)) * KF_P + ks * 32 + q * 8);
#pragma unroll
        for (int n = 0; n < 5; ++n) acc[j][n] = mfma16(a, bf[n], acc[j][n]);
      }
    }
  }
  // epilogue: partial[block][d][m] (coalesced dwordx4) or atomic fallback
  if (use_partial) {
    float* pb = partial + (size_t)blockIdx.x * KV_PARTIAL_SZ;
#pragma unroll
    for (int j = 0; j < 4; ++j)
#pragma unroll
      for (int n = 0; n < 5; ++n) {
        int m = w * 64 + j * 16 + q * 4;
        int d = n * 16 + (lane & 15);
        *(f4v*)(pb + d * 256 + m) = acc[j][n];
      }
  } else {
    float* pb = kvg + (size_t)b * KV_PARTIAL_SZ;
#pragma unroll
    for (int j = 0; j < 4; ++j)
#pragma unroll
      for (int n = 0; n < 5; ++n) {
        int m = w * 64 + j * 16 + q * 4;
        int d = n * 16 + (lane & 15);
#pragma unroll
        for (int reg = 0; reg < 4; ++reg) atomicAdd(pb + d * 256 + m + reg, acc[j][n][reg]);
      }
  }
}

// ---- reduce partials -> kvg[b][80][256] ----
__global__ __launch_bounds__(256) void kv_reduce(const float* __restrict__ partial,
                                                 float* __restrict__ kvg) {
  int i = blockIdx.x * 256 + threadIdx.x;  // 163840 total
  int b = i / KV_PARTIAL_SZ;
  int r = i - b * KV_PARTIAL_SZ;
  const float* src = partial + (size_t)(b * KV_BLOCKS_PER_B) * KV_PARTIAL_SZ + r;
  float s = 0.f;
#pragma unroll 8
  for (int c = 0; c < KV_BLOCKS_PER_B; ++c) s += src[(size_t)c * KV_PARTIAL_SZ];
  kvg[i] = s;
}

// ---- Kernel QKV: fused phi(q) + qkv GEMM + normalize. grid 1024 = 8b x 128 chunks(64 t) ----
constexpr int QF_P = 264;  // qf pitch (shorts): 256 + 8 pad
__global__ __launch_bounds__(256, 2) void qkv_fused(
    const float* __restrict__ query, const short* __restrict__ oh,
    const short* __restrict__ ol, const float* __restrict__ kvg,
    float* __restrict__ out) {
  __shared__ short qf[64 * QF_P];   // [t][feat] bf16, 33.8 KB (reused for out staging)
  __shared__ short kvt[80 * QF_P];  // [d][feat] bf16, 42.2 KB
  const int tid = threadIdx.x, lane = tid & 63, w = tid >> 6;
  const int b = blockIdx.x >> 7;
  const int t0 = (blockIdx.x & 127) * 64;
  const int q = lane >> 4;

  // stage kv -> kvt bf16 (kvg layout is already [b][d][m])
  {
    const float* kvb = kvg + (size_t)b * KV_PARTIAL_SZ;
#pragma unroll
    for (int i = 0; i < 80; ++i) {
      int e = tid + i * 256;
      int d = e >> 8, m = e & 255;
      kvt[d * QF_P + m] = bf16_rne(kvb[e]);
    }
  }
  // phi(q) for this wave's 16 rows -> qf[t][feat]
  {
    PhiRows P;
    load_phi_rows(query + ((size_t)b * NT + t0 + w * 16) * 64, lane, P);
#pragma unroll
    for (int ft = 0; ft < 8; ++ft) {
      f4v c = phi_xw_tile(P, oh, ol, ft * 16, lane);
      const int col = ft * 16 + (lane & 15);
#pragma unroll
      for (int reg = 0; reg < 4; ++reg) {
        float xw = c[reg];
        int row = w * 16 + q * 4 + reg;
        qf[row * QF_P + col] = bf16_rne((__expf(xw - P.ssr[reg]) + EPSF) * SCALE);
        qf[row * QF_P + 128 + col] = bf16_rne((__expf(-xw - P.ssr[reg]) + EPSF) * SCALE);
      }
    }
  }
  __syncthreads();
  // GEMM: out-tile = qf[w-th t-tile] x kv, K=256
  f4v acc[5];
#pragma unroll
  for (int n = 0; n < 5; ++n) acc[n] = f4v{0.f, 0.f, 0.f, 0.f};
#pragma unroll
  for (int ks = 0; ks < 8; ++ks) {
    s8v a = *(const s8v*)(qf + (w * 16 + (lane & 15)) * QF_P + ks * 32 + q * 8);
#pragma unroll
    for (int n = 0; n < 5; ++n) {
      s8v bf = *(const s8v*)(kvt + (n * 16 + (lane & 15)) * QF_P + ks * 32 + q * 8);
      acc[n] = mfma16(a, bf, acc[n]);
    }
  }
  // denominator: N-tile 4, col 64 (lane&15 == 0) holds den for rows quad*4+reg
  float den_r[4];
#pragma unroll
  for (int reg = 0; reg < 4; ++reg) den_r[reg] = __shfl(acc[4][reg], lane & 48, 64);
  // normalize + stage into this wave's own qf region (its GEMM A-reads are done)
  float* stg = (float*)(qf + w * 16 * QF_P);  // 16x68 f32 = 4352 B < 8448 B region
#pragma unroll
  for (int n = 0; n < 4; ++n)
#pragma unroll
    for (int reg = 0; reg < 4; ++reg) {
      int row = q * 4 + reg;
      int col = n * 16 + (lane & 15);
      stg[row * 68 + col] = acc[n][reg] / den_r[reg];
    }
  // coalesced copy out (wave-private, no barrier needed)
  float* ob = out + ((size_t)b * NT + t0 + w * 16) * 64;
#pragma unroll
  for (int rr = 0; rr < 4; ++rr) {
    int row = rr * 4 + q;
    int c4 = (lane & 15) * 4;
    *(f4v*)(ob + row * 64 + c4) = *(const f4v*)(stg + row * 68 + c4);
  }
}

extern "C" void kernel_launch(void* const* d_in, const int* in_sizes, int n_in,
                              void* d_out, int out_size, void* d_ws, size_t ws_size,
                              hipStream_t stream) {
  const float* query = (const float*)d_in[0];  // [8][8192][64]
  const float* value = (const float*)d_in[1];  // [8][8192][64]
  const float* key   = (const float*)d_in[2];  // [8][8192][64]
  const float* omega = (const float*)d_in[3];  // [128][64]
  float* out = (float*)d_out;

  char* ws = (char*)d_ws;
  short* oh = (short*)ws;                       // 16384 B
  short* ol = (short*)(ws + 16384);             // 16384 B
  float* kvg = (float*)(ws + 32768);            // 8*80*256*4 = 655360 B
  float* partial = (float*)(ws + 32768 + 655360);
  const size_t need = 32768 + 655360 + (size_t)512 * KV_PARTIAL_SZ * 4;  // ~42.6 MB
  const int use_partial = (ws_size >= need) ? 1 : 0;

  setup_omega<<<32, 256, 0, stream>>>(omega, oh, ol);
  if (!use_partial) hipMemsetAsync(kvg, 0, 655360, stream);
  kv_fused<<<NB * KV_BLOCKS_PER_B, 256, 0, stream>>>(key, value, oh, ol, partial, kvg, use_partial);
  if (use_partial) kv_reduce<<<640, 256, 0, stream>>>(partial, kvg);
  qkv_fused<<<NB * 128, 256, 0, stream>>>(query, oh, ol, kvg, out);
}

// Round 3
// 152.333 us; speedup vs baseline: 3.8273x; 1.0956x over previous
//
#include <hip/hip_runtime.h>

// LinearAttention (Performer/FAVOR+): B=8, T=S=8192, F=D=64, M=128 (2M=256 features)
// R3: latency-bound fix — oversubscribe (kv feature-split grid 2048), pre-swizzled
// bf16 kv fragments (qkv needs no kv LDS staging), swapped-operand phi in qkv.
//
// MFMA 16x16x32 bf16 layouts (measured, learn_hip m89/m91):
//   A-frag: lane holds A[m = lane&15][k = (lane>>4)*8 + j], j=0..7
//   B-frag: lane holds B[k = (lane>>4)*8 + j][n = lane&15]
//   C/D   : lane holds D[row = (lane>>4)*4 + reg][col = lane&15], reg=0..3

constexpr int NB = 8;
constexpr int NT = 8192;
constexpr float EPSF = 1e-9f;
constexpr float SCALE = 0.0625f;  // 1/sqrt(2*128)

typedef short s8v __attribute__((ext_vector_type(8)));
typedef short s4v __attribute__((ext_vector_type(4)));
typedef float f4v __attribute__((ext_vector_type(4)));

__device__ inline f4v mfma16(s8v a, s8v b, f4v c) {
  return __builtin_amdgcn_mfma_f32_16x16x32_bf16(a, b, c, 0, 0, 0);
}

__device__ inline short bf16_rne(float f) {
  unsigned u = __builtin_bit_cast(unsigned, f);
  u += 0x7fffu + ((u >> 16) & 1u);
  return (short)(u >> 16);
}
__device__ inline float bf16_to_f(short h) {
  unsigned u = ((unsigned)(unsigned short)h) << 16;
  return __builtin_bit_cast(float, u);
}

// ---- setup: split omega into bf16 hi/lo (Markidis 3-term split keeps the
// pre-exp x.omega GEMM at ~fp32 accuracy) ----
__global__ void setup_omega(const float* __restrict__ omega,
                            short* __restrict__ oh, short* __restrict__ ol) {
  int i = blockIdx.x * 256 + threadIdx.x;
  if (i >= 128 * 64) return;
  float w = omega[i];
  short h = bf16_rne(w);
  oh[i] = h;
  ol[i] = bf16_rne(w - bf16_to_f(h));
}

// ---- shared phi helpers ----
struct PhiRows {
  s8v ah0, al0, ah1, al1;  // x fragments (hi/lo) for ksteps 0,1
  float ssr[4];            // |x_row|^2/2 for rows quad*4+reg (C-row indexed)
  float ss;                // |x_row|^2/2 for this lane's own row (lane&15)
};

__device__ inline void split8(f4v a, f4v b, s8v& h, s8v& l) {
  float v[8] = {a.x, a.y, a.z, a.w, b.x, b.y, b.z, b.w};
#pragma unroll
  for (int j = 0; j < 8; ++j) {
    short hh = bf16_rne(v[j]);
    h[j] = hh;
    l[j] = bf16_rne(v[j] - bf16_to_f(hh));
  }
}

__device__ inline void load_phi_rows(const float* __restrict__ xrow_base, int lane, PhiRows& P) {
  const int r = lane & 15, q = lane >> 4;
  const float* p = xrow_base + r * 64 + q * 8;
  f4v u0 = *(const f4v*)(p);
  f4v u1 = *(const f4v*)(p + 4);
  f4v u2 = *(const f4v*)(p + 32);
  f4v u3 = *(const f4v*)(p + 36);
  float ss = u0.x * u0.x + u0.y * u0.y + u0.z * u0.z + u0.w * u0.w
           + u1.x * u1.x + u1.y * u1.y + u1.z * u1.z + u1.w * u1.w
           + u2.x * u2.x + u2.y * u2.y + u2.z * u2.z + u2.w * u2.w
           + u3.x * u3.x + u3.y * u3.y + u3.z * u3.z + u3.w * u3.w;
  ss += __shfl_xor(ss, 16, 64);
  ss += __shfl_xor(ss, 32, 64);
  ss *= 0.5f;
  P.ss = ss;
#pragma unroll
  for (int reg = 0; reg < 4; ++reg) P.ssr[reg] = __shfl(ss, q * 4 + reg, 64);
  split8(u0, u1, P.ah0, P.al0);
  split8(u2, u3, P.ah1, P.al1);
}

// xw C-tile, A = x rows (C: row = x-row q*4+reg, col = omega-row lane&15)
__device__ inline f4v phi_xw_tile(const PhiRows& P, const short* __restrict__ oh,
                                  const short* __restrict__ ol, int f0, int lane) {
  const int fr = f0 + (lane & 15);
  const int q = lane >> 4;
  s8v bh0 = *(const s8v*)(oh + fr * 64 + q * 8);
  s8v bh1 = *(const s8v*)(oh + fr * 64 + 32 + q * 8);
  s8v bl0 = *(const s8v*)(ol + fr * 64 + q * 8);
  s8v bl1 = *(const s8v*)(ol + fr * 64 + 32 + q * 8);
  f4v c = {0.f, 0.f, 0.f, 0.f};
  c = mfma16(P.ah0, bh0, c);
  c = mfma16(P.ah1, bh1, c);
  c = mfma16(P.al0, bh0, c);
  c = mfma16(P.al1, bh1, c);
  c = mfma16(P.ah0, bl0, c);
  c = mfma16(P.ah1, bl1, c);
  return c;
}

// xw C-tile, swapped: A = omega rows (C: row = omega-row q*4+reg, col = x-row lane&15).
// Note the x fragments serve as B unchanged: A-frag and B-frag have the same
// per-lane (idx=lane&15, k=quad*8+j) layout.
__device__ inline f4v phi_xw_tile_T(const PhiRows& P, const short* __restrict__ oh,
                                    const short* __restrict__ ol, int f0, int lane) {
  const int fr = f0 + (lane & 15);
  const int q = lane >> 4;
  s8v ah0 = *(const s8v*)(oh + fr * 64 + q * 8);
  s8v ah1 = *(const s8v*)(oh + fr * 64 + 32 + q * 8);
  s8v al0 = *(const s8v*)(ol + fr * 64 + q * 8);
  s8v al1 = *(const s8v*)(ol + fr * 64 + 32 + q * 8);
  f4v c = {0.f, 0.f, 0.f, 0.f};
  c = mfma16(ah0, P.ah0, c);
  c = mfma16(ah1, P.ah1, c);
  c = mfma16(al0, P.ah0, c);
  c = mfma16(al1, P.ah1, c);
  c = mfma16(ah0, P.al0, c);
  c = mfma16(ah1, P.al1, c);
  return c;
}

// ---- Kernel KV: fused phi(k) + kv GEMM ----
// grid 2048 = 8b x 64 s-chunks(128) x 4 omega-quarters. Quarter fq covers omega
// rows [fq*32, fq*32+32) -> 64 local features (32 plus + 32 minus).
// partial[b][chunk][fq][d=0..79][lf=0..63] f32, 5120 floats/block, 42 MB total.
constexpr int KF_P = 72;  // kft/v1t pitch in shorts (s8v-aligned, 2-way-bank-free reads)

__global__ __launch_bounds__(256, 4) void kv_fused(
    const float* __restrict__ key, const float* __restrict__ value,
    const short* __restrict__ oh, const short* __restrict__ ol,
    float* __restrict__ partial, int use_partial) {
  __shared__ short kft[64 * KF_P];  // [lf][s] bf16, 9216 B
  __shared__ short v1t[80 * KF_P];  // [d][s] bf16, 11520 B
  const int tid = threadIdx.x, lane = tid & 63, w = tid >> 6;
  const int b = blockIdx.x >> 8;
  const int cb = blockIdx.x & 255;
  const int chunk = cb >> 2, fq = cb & 3;
  const int s0 = chunk * 128;
  const int q = lane >> 4, r15 = lane & 15;

  // zero v1t pad rows 65..79 (N=80 tile columns beyond [v|1])
  for (int i = tid; i < 15 * KF_P; i += 256) v1t[65 * KF_P + i] = 0;

  f4v acc[5];
#pragma unroll
  for (int n = 0; n < 5; ++n) acc[n] = f4v{0.f, 0.f, 0.f, 0.f};

  for (int sc = 0; sc < 2; ++sc) {
    const int sbase = s0 + sc * 64;
    __syncthreads();  // protect previous iteration's GEMM reads
    // stage v1t[d][s] (transposed, bf16)
    {
      const float* vb = value + ((size_t)b * NT + sbase) * 64;
#pragma unroll
      for (int i = 0; i < 16; ++i) {
        int e = tid + i * 256;
        int s = e >> 6, d = e & 63;
        v1t[d * KF_P + s] = bf16_rne(vb[e]);
      }
      if (tid < 64) v1t[64 * KF_P + tid] = (short)0x3F80;  // bf16(1.0)
    }
    // phi(k): wave w handles s-rows sbase+w*16..+15, both tiles of its quarter
    {
      PhiRows P;
      load_phi_rows(key + ((size_t)b * NT + sbase + w * 16) * 64, lane, P);
#pragma unroll
      for (int ft = 0; ft < 2; ++ft) {
        f4v c = phi_xw_tile(P, oh, ol, fq * 32 + ft * 16, lane);
        s4v pk, nk;
#pragma unroll
        for (int reg = 0; reg < 4; ++reg) {
          float xw = c[reg];
          pk[reg] = bf16_rne((__expf(xw - P.ssr[reg]) + EPSF) * SCALE);
          nk[reg] = bf16_rne((__expf(-xw - P.ssr[reg]) + EPSF) * SCALE);
        }
        const int scol = w * 16 + q * 4;
        *(s4v*)(kft + (ft * 16 + r15) * KF_P + scol) = pk;        // lf = ft*16+r15
        *(s4v*)(kft + (32 + ft * 16 + r15) * KF_P + scol) = nk;   // lf = 32+...
      }
    }
    __syncthreads();
    // GEMM: wave w accumulates local feats lf = w*16..+15 over all 64 s
#pragma unroll
    for (int ks = 0; ks < 2; ++ks) {
      s8v a = *(const s8v*)(kft + (w * 16 + r15) * KF_P + ks * 32 + q * 8);
#pragma unroll
      for (int n = 0; n < 5; ++n) {
        s8v bf = *(const s8v*)(v1t + (n * 16 + r15) * KF_P + ks * 32 + q * 8);
        acc[n] = mfma16(a, bf, acc[n]);
      }
    }
  }
  // epilogue: C row = lf (w*16+q*4+reg), col = d (n*16+r15)
  if (use_partial) {
    float* pb = partial + (size_t)blockIdx.x * 5120;
#pragma unroll
    for (int n = 0; n < 5; ++n) {
      int d = n * 16 + r15;
      *(f4v*)(pb + d * 64 + w * 16 + q * 4) = acc[n];
    }
  } else {
    float* pb = partial + ((size_t)(b * 4 + fq)) * 5120;
#pragma unroll
    for (int n = 0; n < 5; ++n) {
      int d = n * 16 + r15;
#pragma unroll
      for (int reg = 0; reg < 4; ++reg)
        atomicAdd(pb + d * 64 + w * 16 + q * 4 + reg, acc[n][reg]);
    }
  }
}

// ---- Kernel finalize: reduce partials -> kv bf16 in B-fragment order ----
// kvfrag[b][fid=ks*5+n][lane][j]: lane holds B[k=ks*32+(lane>>4)*8+j][d=n*16+(lane&15)]
// so qkv loads it as one coalesced s8v per (ks,n).
__global__ __launch_bounds__(256) void kv_finalize(
    const float* __restrict__ src, short* __restrict__ kvfrag,
    int nchunks, size_t bstride) {
  int i = blockIdx.x * 256 + threadIdx.x;  // 163840 outputs
  int b = i / 20480;
  int rem = i - b * 20480;
  int fid = rem >> 9;
  int lane = (rem >> 3) & 63;
  int j = rem & 7;
  int ks = fid / 5, n = fid - ks * 5;
  int r = lane & 15, q = lane >> 4;
  int d = n * 16 + r;
  int k = ks * 32 + q * 8 + j;                     // global feature m
  int fq = (k >> 5) & 3;
  int lf = (k & 31) + ((k >> 7) << 5);
  const float* p = src + (size_t)b * bstride + fq * 5120 + d * 64 + lf;
  float s = 0.f;
#pragma unroll 8
  for (int c = 0; c < nchunks; ++c) s += p[(size_t)c * 20480];
  kvfrag[i] = bf16_rne(s);
}

// ---- Kernel QKV: fused phi(q) + qkv GEMM + normalize ----
// grid 1024 = 8b x 128 t-chunks(64). No kv staging (global B-frags), no
// cross-wave dependencies; one barrier for safety on qf.
constexpr int QF_P = 264;  // qf pitch (shorts): 256 + 8 pad
__global__ __launch_bounds__(256, 4) void qkv_fused(
    const float* __restrict__ query, const short* __restrict__ oh,
    const short* __restrict__ ol, const short* __restrict__ kvfrag,
    float* __restrict__ out) {
  __shared__ __align__(16) short qf[64 * QF_P];  // [t][feat] bf16, 33792 B
  const int tid = threadIdx.x, lane = tid & 63, w = tid >> 6;
  const int b = blockIdx.x >> 7;
  const int t0 = (blockIdx.x & 127) * 64;
  const int q = lane >> 4, r15 = lane & 15;

  // phi(q), swapped operands: C row = omega-row, col = t -> packed s4v writes
  {
    PhiRows P;
    load_phi_rows(query + ((size_t)b * NT + t0 + w * 16) * 64, lane, P);
    const int t_loc = w * 16 + r15;
#pragma unroll
    for (int ft = 0; ft < 8; ++ft) {
      f4v c = phi_xw_tile_T(P, oh, ol, ft * 16, lane);
      s4v pk, nk;
#pragma unroll
      for (int reg = 0; reg < 4; ++reg) {
        float xw = c[reg];  // feature ft*16+q*4+reg for x-row r15 (own ss)
        pk[reg] = bf16_rne((__expf(xw - P.ss) + EPSF) * SCALE);
        nk[reg] = bf16_rne((__expf(-xw - P.ss) + EPSF) * SCALE);
      }
      *(s4v*)(qf + t_loc * QF_P + ft * 16 + q * 4) = pk;
      *(s4v*)(qf + t_loc * QF_P + 128 + ft * 16 + q * 4) = nk;
    }
  }
  __syncthreads();
  // GEMM: wave w's A rows = its own 16 t-rows; B-frags straight from global (L2)
  f4v acc[5];
#pragma unroll
  for (int n = 0; n < 5; ++n) acc[n] = f4v{0.f, 0.f, 0.f, 0.f};
  const short* kvb = kvfrag + (size_t)b * 40 * 512;
#pragma unroll
  for (int ks = 0; ks < 8; ++ks) {
    s8v a = *(const s8v*)(qf + (w * 16 + r15) * QF_P + ks * 32 + q * 8);
#pragma unroll
    for (int n = 0; n < 5; ++n) {
      s8v bf = *(const s8v*)(kvb + ((size_t)(ks * 5 + n)) * 512 + lane * 8);
      acc[n] = mfma16(a, bf, acc[n]);
    }
  }
  // denominator: N-tile 4 col 0 (d=64) holds den for rows q*4+reg
  float den_r[4];
#pragma unroll
  for (int reg = 0; reg < 4; ++reg) den_r[reg] = __shfl(acc[4][reg], lane & 48, 64);
  // normalize + stage into this wave's own qf region (its A-reads are done)
  float* stg = (float*)(qf + w * 16 * QF_P);  // 16x68 f32 = 4352 B < 8448 B region
#pragma unroll
  for (int n = 0; n < 4; ++n)
#pragma unroll
    for (int reg = 0; reg < 4; ++reg) {
      int row = q * 4 + reg;
      int col = n * 16 + r15;
      stg[row * 68 + col] = acc[n][reg] / den_r[reg];
    }
  // coalesced copy out (wave-private)
  float* ob = out + ((size_t)b * NT + t0 + w * 16) * 64;
#pragma unroll
  for (int rr = 0; rr < 4; ++rr) {
    int row = rr * 4 + q;
    int c4 = r15 * 4;
    *(f4v*)(ob + row * 64 + c4) = *(const f4v*)(stg + row * 68 + c4);
  }
}

extern "C" void kernel_launch(void* const* d_in, const int* in_sizes, int n_in,
                              void* d_out, int out_size, void* d_ws, size_t ws_size,
                              hipStream_t stream) {
  const float* query = (const float*)d_in[0];  // [8][8192][64]
  const float* value = (const float*)d_in[1];  // [8][8192][64]
  const float* key   = (const float*)d_in[2];  // [8][8192][64]
  const float* omega = (const float*)d_in[3];  // [128][64]
  float* out = (float*)d_out;

  char* ws = (char*)d_ws;
  short* oh = (short*)ws;                        // 16384 B
  short* ol = (short*)(ws + 16384);              // 16384 B
  short* kvfrag = (short*)(ws + 32768);          // 8*40*512*2 = 327680 B
  float* partial = (float*)(ws + 32768 + 327680);
  const size_t need_full = 32768 + 327680 + (size_t)2048 * 5120 * 4;  // ~42.3 MB
  const int use_partial = (ws_size >= need_full) ? 1 : 0;

  setup_omega<<<32, 256, 0, stream>>>(omega, oh, ol);
  if (!use_partial) {
    hipMemsetAsync(partial, 0, (size_t)8 * 4 * 5120 * 4, stream);  // atomic targets
  }
  kv_fused<<<2048, 256, 0, stream>>>(key, value, oh, ol, partial, use_partial);
  if (use_partial) {
    kv_finalize<<<640, 256, 0, stream>>>(partial, kvfrag, 64, (size_t)64 * 20480);
  } else {
    kv_finalize<<<640, 256, 0, stream>>>(partial, kvfrag, 1, (size_t)20480);
  }
  qkv_fused<<<1024, 256, 0, stream>>>(query, oh, ol, kvfrag, out);
}

// Round 4
// 143.330 us; speedup vs baseline: 4.0677x; 1.0628x over previous
//
#include <hip/hip_runtime.h>

// LinearAttention (Performer/FAVOR+): B=8, T=S=8192, F=D=64, M=128 (2M=256 features)
// R4: bf16 partials (halve kv-chain traffic), half-split kv (2x not 4x input dup),
// coalesced finalize, barrier-free qkv.
//
// MFMA 16x16x32 bf16 layouts (measured, learn_hip m89/m91):
//   A-frag: lane holds A[m = lane&15][k = (lane>>4)*8 + j], j=0..7
//   B-frag: lane holds B[k = (lane>>4)*8 + j][n = lane&15]
//   C/D   : lane holds D[row = (lane>>4)*4 + reg][col = lane&15], reg=0..3

constexpr int NB = 8;
constexpr int NT = 8192;
constexpr float EPSF = 1e-9f;
constexpr float SCALE = 0.0625f;  // 1/sqrt(2*128)

typedef short s8v __attribute__((ext_vector_type(8)));
typedef short s4v __attribute__((ext_vector_type(4)));
typedef float f4v __attribute__((ext_vector_type(4)));

__device__ inline f4v mfma16(s8v a, s8v b, f4v c) {
  return __builtin_amdgcn_mfma_f32_16x16x32_bf16(a, b, c, 0, 0, 0);
}

__device__ inline short bf16_rne(float f) {
  unsigned u = __builtin_bit_cast(unsigned, f);
  u += 0x7fffu + ((u >> 16) & 1u);
  return (short)(u >> 16);
}
__device__ inline float bf16_to_f(short h) {
  unsigned u = ((unsigned)(unsigned short)h) << 16;
  return __builtin_bit_cast(float, u);
}

// ---- setup: split omega into bf16 hi/lo (Markidis 3-term split keeps the
// pre-exp x.omega GEMM at ~fp32 accuracy) ----
__global__ void setup_omega(const float* __restrict__ omega,
                            short* __restrict__ oh, short* __restrict__ ol) {
  int i = blockIdx.x * 256 + threadIdx.x;
  if (i >= 128 * 64) return;
  float w = omega[i];
  short h = bf16_rne(w);
  oh[i] = h;
  ol[i] = bf16_rne(w - bf16_to_f(h));
}

// ---- shared phi helpers ----
struct PhiRows {
  s8v ah0, al0, ah1, al1;  // x fragments (hi/lo) for ksteps 0,1
  float ssr[4];            // |x_row|^2/2 for rows quad*4+reg (C-row indexed)
  float ss;                // |x_row|^2/2 for this lane's own row (lane&15)
};

__device__ inline void split8(f4v a, f4v b, s8v& h, s8v& l) {
  float v[8] = {a.x, a.y, a.z, a.w, b.x, b.y, b.z, b.w};
#pragma unroll
  for (int j = 0; j < 8; ++j) {
    short hh = bf16_rne(v[j]);
    h[j] = hh;
    l[j] = bf16_rne(v[j] - bf16_to_f(hh));
  }
}

__device__ inline void load_phi_rows(const float* __restrict__ xrow_base, int lane, PhiRows& P) {
  const int r = lane & 15, q = lane >> 4;
  const float* p = xrow_base + r * 64 + q * 8;
  f4v u0 = *(const f4v*)(p);
  f4v u1 = *(const f4v*)(p + 4);
  f4v u2 = *(const f4v*)(p + 32);
  f4v u3 = *(const f4v*)(p + 36);
  float ss = u0.x * u0.x + u0.y * u0.y + u0.z * u0.z + u0.w * u0.w
           + u1.x * u1.x + u1.y * u1.y + u1.z * u1.z + u1.w * u1.w
           + u2.x * u2.x + u2.y * u2.y + u2.z * u2.z + u2.w * u2.w
           + u3.x * u3.x + u3.y * u3.y + u3.z * u3.z + u3.w * u3.w;
  ss += __shfl_xor(ss, 16, 64);
  ss += __shfl_xor(ss, 32, 64);
  ss *= 0.5f;
  P.ss = ss;
#pragma unroll
  for (int reg = 0; reg < 4; ++reg) P.ssr[reg] = __shfl(ss, q * 4 + reg, 64);
  split8(u0, u1, P.ah0, P.al0);
  split8(u2, u3, P.ah1, P.al1);
}

// xw C-tile, A = x rows (C: row = x-row q*4+reg, col = omega-row lane&15)
__device__ inline f4v phi_xw_tile(const PhiRows& P, const short* __restrict__ oh,
                                  const short* __restrict__ ol, int f0, int lane) {
  const int fr = f0 + (lane & 15);
  const int q = lane >> 4;
  s8v bh0 = *(const s8v*)(oh + fr * 64 + q * 8);
  s8v bh1 = *(const s8v*)(oh + fr * 64 + 32 + q * 8);
  s8v bl0 = *(const s8v*)(ol + fr * 64 + q * 8);
  s8v bl1 = *(const s8v*)(ol + fr * 64 + 32 + q * 8);
  f4v c = {0.f, 0.f, 0.f, 0.f};
  c = mfma16(P.ah0, bh0, c);
  c = mfma16(P.ah1, bh1, c);
  c = mfma16(P.al0, bh0, c);
  c = mfma16(P.al1, bh1, c);
  c = mfma16(P.ah0, bl0, c);
  c = mfma16(P.ah1, bl1, c);
  return c;
}

// xw C-tile, swapped: A = omega rows (C: row = omega-row q*4+reg, col = x-row lane&15).
// x fragments serve as B unchanged: A-frag and B-frag share the per-lane layout.
__device__ inline f4v phi_xw_tile_T(const PhiRows& P, const short* __restrict__ oh,
                                    const short* __restrict__ ol, int f0, int lane) {
  const int fr = f0 + (lane & 15);
  const int q = lane >> 4;
  s8v ah0 = *(const s8v*)(oh + fr * 64 + q * 8);
  s8v ah1 = *(const s8v*)(oh + fr * 64 + 32 + q * 8);
  s8v al0 = *(const s8v*)(ol + fr * 64 + q * 8);
  s8v al1 = *(const s8v*)(ol + fr * 64 + 32 + q * 8);
  f4v c = {0.f, 0.f, 0.f, 0.f};
  c = mfma16(ah0, P.ah0, c);
  c = mfma16(ah1, P.ah1, c);
  c = mfma16(al0, P.ah0, c);
  c = mfma16(al1, P.ah1, c);
  c = mfma16(ah0, P.al0, c);
  c = mfma16(ah1, P.al1, c);
  return c;
}

// ---- Kernel KV: fused phi(k) + kv GEMM ----
// grid 1024 = 8b x 64 s-chunks(128) x 2 omega-halves. Half fh covers omega rows
// [fh*64, fh*64+64) -> 128 local features (64 plus + 64 minus).
// partial[bi = b*128 + chunk*2 + fh][d=0..79][lf=0..127] bf16 -> 21 MB total.
constexpr int KF_P = 72;  // kft/v1t pitch in shorts

__global__ __launch_bounds__(256, 4) void kv_fused(
    const float* __restrict__ key, const float* __restrict__ value,
    const short* __restrict__ oh, const short* __restrict__ ol,
    short* __restrict__ partial, float* __restrict__ kvacc, int use_partial) {
  __shared__ short kft[128 * KF_P];  // [lf][s] bf16, 18432 B
  __shared__ short v1t[80 * KF_P];   // [d][s] bf16, 11520 B
  const int tid = threadIdx.x, lane = tid & 63, w = tid >> 6;
  const int b = blockIdx.x >> 7;
  const int cb = blockIdx.x & 127;
  const int fh = cb & 1;
  const int s0 = (cb >> 1) * 128;
  const int q = lane >> 4, r15 = lane & 15;

  // zero v1t pad rows 65..79 (N=80 tile columns beyond [v|1])
  for (int i = tid; i < 15 * KF_P; i += 256) v1t[65 * KF_P + i] = 0;

  f4v acc[2][5];
#pragma unroll
  for (int j = 0; j < 2; ++j)
#pragma unroll
    for (int n = 0; n < 5; ++n) acc[j][n] = f4v{0.f, 0.f, 0.f, 0.f};

  for (int sc = 0; sc < 2; ++sc) {
    const int sbase = s0 + sc * 64;
    __syncthreads();  // protect previous iteration's GEMM reads
    // stage v1t[d][s] (transposed, bf16); f4v global loads
    {
      const float* vb = value + ((size_t)b * NT + sbase) * 64;
#pragma unroll
      for (int i = 0; i < 4; ++i) {
        int e4 = tid + i * 256;           // f4v index
        f4v v4 = ((const f4v*)vb)[e4];
        int s = e4 >> 4, d0 = (e4 & 15) * 4;
        v1t[(d0 + 0) * KF_P + s] = bf16_rne(v4.x);
        v1t[(d0 + 1) * KF_P + s] = bf16_rne(v4.y);
        v1t[(d0 + 2) * KF_P + s] = bf16_rne(v4.z);
        v1t[(d0 + 3) * KF_P + s] = bf16_rne(v4.w);
      }
      if (tid < 64) v1t[64 * KF_P + tid] = (short)0x3F80;  // bf16(1.0)
    }
    // phi(k): wave w handles s-rows sbase+w*16..+15, 4 tiles of its half
    {
      PhiRows P;
      load_phi_rows(key + ((size_t)b * NT + sbase + w * 16) * 64, lane, P);
#pragma unroll
      for (int ft = 0; ft < 4; ++ft) {
        f4v c = phi_xw_tile(P, oh, ol, fh * 64 + ft * 16, lane);
        s4v pk, nk;
#pragma unroll
        for (int reg = 0; reg < 4; ++reg) {
          float xw = c[reg];
          pk[reg] = bf16_rne((__expf(xw - P.ssr[reg]) + EPSF) * SCALE);
          nk[reg] = bf16_rne((__expf(-xw - P.ssr[reg]) + EPSF) * SCALE);
        }
        const int scol = w * 16 + q * 4;
        *(s4v*)(kft + (ft * 16 + r15) * KF_P + scol) = pk;        // lf in [0,64)
        *(s4v*)(kft + (64 + ft * 16 + r15) * KF_P + scol) = nk;   // lf in [64,128)
      }
    }
    __syncthreads();
    // GEMM: wave w accumulates local feats lf = w*32..+31 over all 64 s
#pragma unroll
    for (int ks = 0; ks < 2; ++ks) {
      s8v bf[5];
#pragma unroll
      for (int n = 0; n < 5; ++n)
        bf[n] = *(const s8v*)(v1t + (n * 16 + r15) * KF_P + ks * 32 + q * 8);
#pragma unroll
      for (int j = 0; j < 2; ++j) {
        s8v a = *(const s8v*)(kft + (w * 32 + j * 16 + r15) * KF_P + ks * 32 + q * 8);
#pragma unroll
        for (int n = 0; n < 5; ++n) acc[j][n] = mfma16(a, bf[n], acc[j][n]);
      }
    }
  }
  // epilogue: C row = lf (w*32+j*16+q*4+reg), col = d (n*16+r15)
  if (use_partial) {
    short* pb = partial + (size_t)blockIdx.x * (80 * 128);
#pragma unroll
    for (int j = 0; j < 2; ++j)
#pragma unroll
      for (int n = 0; n < 5; ++n) {
        int d = n * 16 + r15;
        int lf = w * 32 + j * 16 + q * 4;
        s4v pk;
#pragma unroll
        for (int reg = 0; reg < 4; ++reg) pk[reg] = bf16_rne(acc[j][n][reg]);
        *(s4v*)(pb + d * 128 + lf) = pk;
      }
  } else {
    float* pb = kvacc + (size_t)b * (80 * 256);
#pragma unroll
    for (int j = 0; j < 2; ++j)
#pragma unroll
      for (int n = 0; n < 5; ++n) {
        int d = n * 16 + r15;
        int lf = w * 32 + j * 16 + q * 4;
#pragma unroll
        for (int reg = 0; reg < 4; ++reg) {
          int lfx = lf + reg;
          int m = ((lfx & 63) + fh * 64) + 128 * (lfx >> 6);
          atomicAdd(pb + d * 256 + m, acc[j][n][reg]);
        }
      }
  }
}

// ---- Kernel finalize: reduce bf16 partials -> kv bf16 in B-fragment order ----
// kvfrag[b][fid=ks*5+n][lane][j]: lane holds B[k=ks*32+(lane>>4)*8+j][d=n*16+(lane&15)]
__global__ __launch_bounds__(256) void kv_finalize(
    const short* __restrict__ partial, const float* __restrict__ kvacc,
    short* __restrict__ kvfrag, int use_partial) {
  int i = blockIdx.x * 256 + threadIdx.x;  // 163840 outputs: (b, d, m) m-fastest
  int b = i / 20480;
  int rem = i - b * 20480;
  int d = rem >> 8;
  int m = rem & 255;
  float s = 0.f;
  if (use_partial) {
    int o = m & 127, sg = m >> 7;
    int fh = o >> 6;
    int lf = (o & 63) + (sg << 6);
    const short* p = partial + ((size_t)(b * 128 + fh)) * (80 * 128) + d * 128 + lf;
#pragma unroll 8
    for (int c = 0; c < 64; ++c) s += bf16_to_f(p[(size_t)c * 2 * (80 * 128)]);
  } else {
    s = kvacc[(size_t)(b * 80 + d) * 256 + m];
  }
  int ks = m >> 5, qq = (m >> 3) & 3, j = m & 7;
  int n = d >> 4, r = d & 15;
  int lane = qq * 16 + r;
  kvfrag[(((size_t)b * 40 + ks * 5 + n) * 64 + lane) * 8 + j] = bf16_rne(s);
}

// ---- Kernel QKV: fused phi(q) + qkv GEMM + normalize ----
// grid 1024 = 8b x 128 t-chunks(64). qf is wave-private (phi writes rows
// w*16..+15; GEMM A-frags read only those) -> NO barriers at all.
constexpr int QF_P = 264;  // qf pitch (shorts): 256 + 8 pad
__global__ __launch_bounds__(256, 4) void qkv_fused(
    const float* __restrict__ query, const short* __restrict__ oh,
    const short* __restrict__ ol, const short* __restrict__ kvfrag,
    float* __restrict__ out) {
  __shared__ __align__(16) short qf[64 * QF_P];  // [t][feat] bf16, 33792 B
  const int tid = threadIdx.x, lane = tid & 63, w = tid >> 6;
  const int b = blockIdx.x >> 7;
  const int t0 = (blockIdx.x & 127) * 64;
  const int q = lane >> 4, r15 = lane & 15;

  // phi(q), swapped operands: C row = omega-row, col = t -> packed s4v writes
  {
    PhiRows P;
    load_phi_rows(query + ((size_t)b * NT + t0 + w * 16) * 64, lane, P);
    const int t_loc = w * 16 + r15;
#pragma unroll
    for (int ft = 0; ft < 8; ++ft) {
      f4v c = phi_xw_tile_T(P, oh, ol, ft * 16, lane);
      s4v pk, nk;
#pragma unroll
      for (int reg = 0; reg < 4; ++reg) {
        float xw = c[reg];  // feature ft*16+q*4+reg for x-row r15 (own ss)
        pk[reg] = bf16_rne((__expf(xw - P.ss) + EPSF) * SCALE);
        nk[reg] = bf16_rne((__expf(-xw - P.ss) + EPSF) * SCALE);
      }
      *(s4v*)(qf + t_loc * QF_P + ft * 16 + q * 4) = pk;
      *(s4v*)(qf + t_loc * QF_P + 128 + ft * 16 + q * 4) = nk;
    }
  }
  // GEMM: wave w's A rows = its own 16 t-rows; B-frags straight from global (L2)
  f4v acc[5];
#pragma unroll
  for (int n = 0; n < 5; ++n) acc[n] = f4v{0.f, 0.f, 0.f, 0.f};
  const short* kvb = kvfrag + (size_t)b * 40 * 512;
#pragma unroll
  for (int ks = 0; ks < 8; ++ks) {
    s8v a = *(const s8v*)(qf + (w * 16 + r15) * QF_P + ks * 32 + q * 8);
#pragma unroll
    for (int n = 0; n < 5; ++n) {
      s8v bf = *(const s8v*)(kvb + ((size_t)(ks * 5 + n)) * 512 + lane * 8);
      acc[n] = mfma16(a, bf, acc[n]);
    }
  }
  // denominator: N-tile 4 col 0 (d=64) holds den for rows q*4+reg
  float den_r[4];
#pragma unroll
  for (int reg = 0; reg < 4; ++reg) den_r[reg] = __shfl(acc[4][reg], lane & 48, 64);
  // normalize + stage into this wave's own qf region (its A-reads are done)
  float* stg = (float*)(qf + w * 16 * QF_P);  // 16x68 f32 = 4352 B < 8448 B region
#pragma unroll
  for (int n = 0; n < 4; ++n)
#pragma unroll
    for (int reg = 0; reg < 4; ++reg) {
      int row = q * 4 + reg;
      int col = n * 16 + r15;
      stg[row * 68 + col] = acc[n][reg] / den_r[reg];
    }
  // coalesced copy out (wave-private)
  float* ob = out + ((size_t)b * NT + t0 + w * 16) * 64;
#pragma unroll
  for (int rr = 0; rr < 4; ++rr) {
    int row = rr * 4 + q;
    int c4 = r15 * 4;
    *(f4v*)(ob + row * 64 + c4) = *(const f4v*)(stg + row * 68 + c4);
  }
}

extern "C" void kernel_launch(void* const* d_in, const int* in_sizes, int n_in,
                              void* d_out, int out_size, void* d_ws, size_t ws_size,
                              hipStream_t stream) {
  const float* query = (const float*)d_in[0];  // [8][8192][64]
  const float* value = (const float*)d_in[1];  // [8][8192][64]
  const float* key   = (const float*)d_in[2];  // [8][8192][64]
  const float* omega = (const float*)d_in[3];  // [128][64]
  float* out = (float*)d_out;

  char* ws = (char*)d_ws;
  short* oh = (short*)ws;                        // 16384 B
  short* ol = (short*)(ws + 16384);              // 16384 B
  short* kvfrag = (short*)(ws + 32768);          // 8*40*512*2 = 327680 B
  short* partial = (short*)(ws + 360448);        // 1024*80*128*2 = 20971520 B
  float* kvacc = (float*)(ws + 360448);          // fallback: 8*80*256*4 = 655360 B
  const size_t need_full = 360448 + (size_t)1024 * 80 * 128 * 2;  // ~21.3 MB
  const int use_partial = (ws_size >= need_full) ? 1 : 0;

  setup_omega<<<32, 256, 0, stream>>>(omega, oh, ol);
  if (!use_partial) {
    hipMemsetAsync(kvacc, 0, (size_t)8 * 80 * 256 * 4, stream);  // atomic targets
  }
  kv_fused<<<1024, 256, 0, stream>>>(key, value, oh, ol, partial, kvacc, use_partial);
  kv_finalize<<<640, 256, 0, stream>>>(partial, kvacc, kvfrag, use_partial);
  qkv_fused<<<1024, 256, 0, stream>>>(query, oh, ol, kvfrag, out);
}